// Round 1
// baseline (242.114 us; speedup 1.0000x reference)
//
#include <hip/hip_runtime.h>
#include <hip/hip_bf16.h>

// B=4, S=2048, D=1024, H=16, HD=64.
// Input dtype detected inline (fp32 vs bf16); compute pipeline is bf16 MFMA.
#define B_  4
#define S_  2048
#define D_  1024
#define H_  16
#define HD_ 64

using short4_ = __attribute__((ext_vector_type(4))) short;
using short8  = __attribute__((ext_vector_type(8))) short;
using floatx4 = __attribute__((ext_vector_type(4))) float;

#define MFMA16(a, b, c) __builtin_amdgcn_mfma_f32_16x16x32_bf16((a), (b), (c), 0, 0, 0)

// softmax scale folded into Q at QKV-GEMM epilogue: (1/sqrt(64)) * log2(e)
#define QSCALE (0.125f * 1.4426950408889634f)

static __device__ __forceinline__ short f_to_bf16(float f) {
    __hip_bfloat16 h = __float2bfloat16(f);
    short s;
    __builtin_memcpy(&s, &h, 2);
    return s;
}

// async global->LDS, 16B per lane; LDS dst must be wave-uniform base + lane*16.
static __device__ __forceinline__ void gl_lds16(const short* g, short* l) {
    __builtin_amdgcn_global_load_lds(
        (const __attribute__((address_space(1))) void*)g,
        (__attribute__((address_space(3))) void*)l, 16, 0, 0);
}

// Inline dtype detect: lanes 0..63 read x's first 64 dwords as fp32.
static __device__ __forceinline__ bool detect_fp32(const unsigned int* __restrict__ xraw) {
    const float f = __uint_as_float(xraw[threadIdx.x & 63]);
    const bool weird = !(f == f) || fabsf(f) > 1e30f;
    return __ballot(weird) == 0ull;
}

// ---------------------------------------------------------------------------
// Merged convert: virtual concat [x | Wq | Wk | Wv | Wo] -> contiguous
// bf16 [xb | wqkv(3) | wob]. One launch.
// ---------------------------------------------------------------------------
__global__ __launch_bounds__(256) void convert_all_kernel(
    const void* __restrict__ x,  const void* __restrict__ wq,
    const void* __restrict__ wk, const void* __restrict__ wv,
    const void* __restrict__ wo, short* __restrict__ dst,
    const unsigned int* __restrict__ xraw)
{
    const bool isf32 = detect_fp32(xraw);
    const size_t NE = (size_t)B_ * S_ * D_;   // 8388608
    const size_t NW = (size_t)D_ * D_;        // 1048576 = 2^20
    const size_t i = ((size_t)blockIdx.x * 256 + threadIdx.x) * 8;

    const void* src;
    size_t off;
    if (i < NE) { src = x; off = i; }
    else {
        const size_t j = i - NE;
        const int r = (int)(j >> 20);
        src = (r == 0) ? wq : (r == 1) ? wk : (r == 2) ? wv : wo;
        off = j & (NW - 1);
    }

    if (isf32) {
        const float* s = (const float*)src + off;
        short8 o;
#pragma unroll
        for (int j2 = 0; j2 < 8; ++j2) o[j2] = f_to_bf16(s[j2]);
        *(short8*)(dst + i) = o;
    } else {
        *(short8*)(dst + i) = *(const short8*)((const short*)src + off);
    }
}

// ---------------------------------------------------------------------------
// Fused QKV GEMM -- 256x256 tile, 8-phase counted-vmcnt pipeline (T3+T4+T5).
// W = concat(Wq,Wk,Wv) rows [3072][1024]. 512 thr / 8 waves; wave = 128x64
// (acc[8][4]). BK=64, double-buffered LDS (128 KiB). Per K-tile: 4 phases,
// each = {12x ds_read_b128 | 1 stage unit (2x global_load_lds) | barrier |
// lgkmcnt(0) | setprio(1) 16 MFMA setprio(0) | barrier}; vmcnt(4) gate only
// at K-tile boundary (2 stage units stay in flight across every barrier).
//
// Stage units & lifetimes (phase order mh-major: p1=(0,0) p2=(0,1) p3=(1,0)
// p4=(1,1)):
//   U0 = A rows {0-63,128-191}  read p1,p2 -> freed after p2, staged at p3
//   U1 = A rows {64-127,192-255} read p3,p4 -> staged next-tile p1
//   U2 = B nh0 rows (prow 0-127) read p1,p3 -> freed after p3, staged at p4
//   U3 = B nh1 rows (prow 128-255) read p2,p4 -> staged next-tile p2
// B rows live nh-permuted in LDS (per-lane global src absorbs the perm;
// global_load_lds dest stays linear). Every phase's stage target is disjoint
// from every concurrently-live read region (verified per phase).
//
// Rows are 64 bf16 = 8 16B-blocks, XOR-swizzled (phys = (logical+row)&7)
// -> conflict-free ds_read_b128 (T2).
// sel==0 (Q): output pre-scaled by QSCALE.
// sel==2 (V): output written as per-head V^T via LDS transpose epilogue.
// ---------------------------------------------------------------------------
#define QKV_PHASE(MH, NH, STAGE_BLOCK, GATE_BLOCK)                              \
  {                                                                             \
    short8 af[4][2], bf[2][2];                                                  \
    _Pragma("unroll")                                                           \
    for (int mi = 0; mi < 4; ++mi) {                                            \
      const int row = wm + (MH)*64 + 16*mi + l15;                               \
      _Pragma("unroll")                                                         \
      for (int ks = 0; ks < 2; ++ks)                                            \
        af[mi][ks] = *(const short8*)&pA[row*64 + ((4*ks + quad + l15)&7)*8];   \
    }                                                                           \
    _Pragma("unroll")                                                           \
    for (int ni = 0; ni < 2; ++ni) {                                            \
      const int prow = (NH)*128 + wn32 + 16*ni + l15;                           \
      _Pragma("unroll")                                                         \
      for (int ks = 0; ks < 2; ++ks)                                            \
        bf[ni][ks] = *(const short8*)&pB[prow*64 + ((4*ks + quad + l15)&7)*8];  \
    }                                                                           \
    STAGE_BLOCK                                                                 \
    __builtin_amdgcn_s_barrier();                                               \
    asm volatile("s_waitcnt lgkmcnt(0)" ::: "memory");                          \
    __builtin_amdgcn_s_setprio(1);                                              \
    _Pragma("unroll")                                                           \
    for (int mi = 0; mi < 4; ++mi)                                              \
      _Pragma("unroll")                                                         \
      for (int ni = 0; ni < 2; ++ni)                                            \
        _Pragma("unroll")                                                       \
        for (int ks = 0; ks < 2; ++ks)                                          \
          acc[(MH)*4+mi][(NH)*2+ni] =                                           \
              MFMA16(af[mi][ks], bf[ni][ks], acc[(MH)*4+mi][(NH)*2+ni]);        \
    __builtin_amdgcn_s_setprio(0);                                              \
    GATE_BLOCK                                                                  \
    __builtin_amdgcn_s_barrier();                                               \
  }

__global__ __launch_bounds__(512, 2) void gemm_qkv256_kernel(
    const short* __restrict__ X, const short* __restrict__ W,
    short* __restrict__ Yq, short* __restrict__ Yk, short* __restrict__ VT)
{
    __shared__ __align__(16) short Lds[65536];   // 128 KiB: 2 buffers x (A 32K + B 32K shorts)

    const int tid  = threadIdx.x;
    const int wave = tid >> 6;
    const int lane = tid & 63;
    const int quad = lane >> 4;
    const int l15  = lane & 15;

    const int mBase = blockIdx.x * 256;
    const int nTot  = blockIdx.y * 256;          // 0..3071
    const int sel   = nTot >> 10;                // 0=q,1=k,2=v

    const int wm   = (wave >> 2) * 128;          // 0 / 128
    const int wn   = (wave & 3) * 64;            // 0,64,128,192
    const int wn32 = (wave & 3) * 32;            // B prow sub-base

    // staging geometry: 8 threads/row, 64 rows per global_load_lds instruction
    const int rS  = tid >> 3;                            // 0..63
    const int sb8 = (((tid & 7) - rS) & 7) * 8;          // swizzled source block

    // A chunk sources (natural row layout): U0={gA0,gA1} U1={gA2,gA3}
    const short* gA0 = X + (size_t)(mBase +   0 + rS) * D_ + sb8;
    const short* gA1 = X + (size_t)(mBase + 128 + rS) * D_ + sb8;
    const short* gA2 = X + (size_t)(mBase +  64 + rS) * D_ + sb8;
    const short* gA3 = X + (size_t)(mBase + 192 + rS) * D_ + sb8;
    // B chunk sources (nh-permuted prow layout): U2={gB0,gB1} U3={gB2,gB3}
    // prow -> logical row: ((prow&127)>>5)*64 + (prow>>7)*32 + (prow&31)
    auto nl = [](int pr) { return ((pr & 127) >> 5) * 64 + (pr >> 7) * 32 + (pr & 31); };
    const short* gB0 = W + (size_t)(nTot + nl(  0 + rS)) * D_ + sb8;
    const short* gB1 = W + (size_t)(nTot + nl( 64 + rS)) * D_ + sb8;
    const short* gB2 = W + (size_t)(nTot + nl(128 + rS)) * D_ + sb8;
    const short* gB3 = W + (size_t)(nTot + nl(192 + rS)) * D_ + sb8;

    floatx4 acc[8][4] = {};

    // ---- prologue: tile0 all units -> buf0; tile1 U0,U2 -> buf1 ------------
    gl_lds16(gA0,      Lds +     0 + tid * 8);   // t0.U0
    gl_lds16(gA1,      Lds +  8192 + tid * 8);
    gl_lds16(gA2,      Lds +  4096 + tid * 8);   // t0.U1
    gl_lds16(gA3,      Lds + 12288 + tid * 8);
    gl_lds16(gB0,      Lds + 16384 + tid * 8);   // t0.U2
    gl_lds16(gB1,      Lds + 20480 + tid * 8);
    gl_lds16(gB2,      Lds + 24576 + tid * 8);   // t0.U3
    gl_lds16(gB3,      Lds + 28672 + tid * 8);
    gl_lds16(gA0 + 64, Lds + 32768 +     0 + tid * 8);   // t1.U0
    gl_lds16(gA1 + 64, Lds + 32768 +  8192 + tid * 8);
    gl_lds16(gB0 + 64, Lds + 32768 + 16384 + tid * 8);   // t1.U2
    gl_lds16(gB1 + 64, Lds + 32768 + 20480 + tid * 8);
    asm volatile("s_waitcnt vmcnt(4)" ::: "memory");     // t0 landed; t1 half in flight
    __builtin_amdgcn_s_barrier();

    // ---- main loop: 16 K-tiles, 4 phases each ------------------------------
#pragma unroll 2
    for (int t = 0; t < 16; ++t) {
        short* pA = Lds + (t & 1) * 32768;
        short* pB = pA + 16384;
        short* qA = Lds + ((t + 1) & 1) * 32768;
        short* qB = qA + 16384;
        const int k1 = (t + 1) * 64;
        const int k2 = (t + 2) * 64;
        const bool s1 = (t + 1) < 16;
        const bool s2 = (t + 2) < 16;

        QKV_PHASE(0, 0,
            { if (s1) { gl_lds16(gA2 + k1, qA +  4096 + tid * 8);
                        gl_lds16(gA3 + k1, qA + 12288 + tid * 8); } },   // (t+1).U1
            {})
        QKV_PHASE(0, 1,
            { if (s1) { gl_lds16(gB2 + k1, qB +  8192 + tid * 8);
                        gl_lds16(gB3 + k1, qB + 12288 + tid * 8); } },   // (t+1).U3
            {})
        QKV_PHASE(1, 0,
            { if (s2) { gl_lds16(gA0 + k2, pA +        tid * 8);
                        gl_lds16(gA1 + k2, pA +  8192 + tid * 8); } },   // (t+2).U0 (A Q0,Q2 freed @p2)
            {})
        QKV_PHASE(1, 1,
            { if (s2) { gl_lds16(gB0 + k2, pB +        tid * 8);
                        gl_lds16(gB1 + k2, pB +  4096 + tid * 8); } },   // (t+2).U2 (B nh0 freed @p3)
            { if (s2) asm volatile("s_waitcnt vmcnt(4)" ::: "memory");
              else    asm volatile("s_waitcnt vmcnt(0)" ::: "memory"); })
    }

    // ---- epilogue ----------------------------------------------------------
    if (sel < 2) {
        short* Y = (sel == 0) ? Yq : Yk;
        const float osc = (sel == 0) ? QSCALE : 1.0f;
        const int nBase = nTot & 1023;
#pragma unroll
        for (int mh = 0; mh < 2; ++mh)
#pragma unroll
        for (int mi = 0; mi < 4; ++mi)
#pragma unroll
        for (int nh = 0; nh < 2; ++nh)
#pragma unroll
        for (int ni = 0; ni < 2; ++ni)
#pragma unroll
        for (int r = 0; r < 4; ++r) {
            const size_t idx =
                (size_t)(mBase + wm + mh * 64 + 16 * mi + 4 * quad + r) * D_ +
                (nBase + wn + nh * 32 + 16 * ni + l15);
            Y[idx] = f_to_bf16(acc[mh * 4 + mi][nh * 2 + ni][r] * osc);
        }
    } else {
        // V^T epilogue: LDS transpose (Tb = 128 chans x 256 m, stride 264),
        // two halves of 128 channels; coalesced 512B-row writes to VT.
        const int bb = mBase >> 11;     // batch
        const int s0 = mBase & 2047;    // seq base
        const int nBase = nTot & 1023;
        short* Tb = Lds;
        const int myhalf = wn >> 7;
#pragma unroll
        for (int half = 0; half < 2; ++half) {
            __syncthreads();  // LDS free (k-loop drained / previous half read)
            if (myhalf == half) {
#pragma unroll
                for (int nh = 0; nh < 2; ++nh)
#pragma unroll
                for (int ni = 0; ni < 2; ++ni)
#pragma unroll
                for (int mh = 0; mh < 2; ++mh)
#pragma unroll
                for (int mi = 0; mi < 4; ++mi) {
                    short4_ v4;
#pragma unroll
                    for (int r = 0; r < 4; ++r)
                        v4[r] = f_to_bf16(acc[mh * 4 + mi][nh * 2 + ni][r]);
                    const int cl = (wn & 64) + nh * 32 + 16 * ni + l15;
                    *(short4_*)&Tb[cl * 264 + wm + mh * 64 + 16 * mi + 4 * quad] = v4;
                }
            }
            __syncthreads();
#pragma unroll
            for (int p = 0; p < 8; ++p) {
                const int t2 = tid + p * 512;
                const int cl = t2 >> 5;           // 0..127
                const int mc = (t2 & 31) * 8;     // 0..248
                const short8 val = *(const short8*)&Tb[cl * 264 + mc];
                const int c  = nBase + half * 128 + cl;   // global channel
                const int hh = c >> 6, hd = c & 63;
                *(short8*)&VT[((size_t)(bb * H_ + hh) * HD_ + hd) * S_ + s0 + mc] = val;
            }
        }
    }
}

// ---------------------------------------------------------------------------
// GEMM: Y = X @ W^T, BK=64 (used for the Wo projection). fp32 out if input
// dtype (detected from xraw) is fp32.
// ---------------------------------------------------------------------------
__global__ __launch_bounds__(256) void gemm_xwT_kernel(
    const short* __restrict__ X, const short* __restrict__ W,
    void* __restrict__ Y, const unsigned int* __restrict__ xraw)
{
    __shared__ __align__(16) short LDS[2 * 128 * 64];
    short* Atile = LDS;
    short* Btile = LDS + 128 * 64;

    const bool f32out = detect_fp32(xraw);

    const int tid  = threadIdx.x;
    const int wave = tid >> 6;
    const int lane = tid & 63;
    const int quad = lane >> 4;
    const int l15  = lane & 15;

    const int mBase = blockIdx.x * 128;
    const int nBase = blockIdx.y * 128;
    const int wm = (wave & 1) * 64;
    const int wn = (wave >> 1) * 64;

    const int rowS = tid >> 3;
    const int colS = (((tid & 7) - rowS) & 7) * 8;
    const short* gA = X + (size_t)(mBase + rowS) * D_ + colS;
    const short* gB = W + (size_t)(nBase + rowS) * D_ + colS;

    floatx4 acc[4][4] = {};

    for (int k0 = 0; k0 < D_; k0 += 64) {
#pragma unroll
        for (int p = 0; p < 4; ++p) {
            gl_lds16(gA + (size_t)(p * 32) * D_ + k0, &Atile[p * 2048 + tid * 8]);
            gl_lds16(gB + (size_t)(p * 32) * D_ + k0, &Btile[p * 2048 + tid * 8]);
        }
        __syncthreads();

#pragma unroll
        for (int ks = 0; ks < 2; ++ks) {
            const int pblk = ((4 * ks + quad + l15) & 7) * 8;
            short8 a[4], b[4];
#pragma unroll
            for (int i = 0; i < 4; ++i) {
                a[i] = *(const short8*)&Atile[(wm + 16 * i + l15) * 64 + pblk];
                b[i] = *(const short8*)&Btile[(wn + 16 * i + l15) * 64 + pblk];
            }
#pragma unroll
            for (int mi = 0; mi < 4; ++mi)
#pragma unroll
                for (int ni = 0; ni < 4; ++ni)
                    acc[mi][ni] = MFMA16(a[mi], b[ni], acc[mi][ni]);
        }
        __syncthreads();
    }

#pragma unroll
    for (int mi = 0; mi < 4; ++mi)
#pragma unroll
        for (int ni = 0; ni < 4; ++ni)
#pragma unroll
            for (int r = 0; r < 4; ++r) {
                const size_t idx =
                    (size_t)(mBase + wm + 16 * mi + quad * 4 + r) * D_ +
                    (nBase + wn + 16 * ni + l15);
                if (f32out) ((float*)Y)[idx] = acc[mi][ni][r];
                else        ((short*)Y)[idx] = f_to_bf16(acc[mi][ni][r]);
            }
}

// ---------------------------------------------------------------------------
// Flash attention, causal. Strips of 64 queries; block handles pair
// {j, 31-j} sequentially -> exactly 33 k-rounds/block (balanced).
// grid = (H, 16 pairs, B): same-(b,h) blocks are 16 apart in linear order
// -> same XCD -> K/VT L2-resident. 1024 blocks = 4/CU (launch_bounds 256,4).
// ---------------------------------------------------------------------------
__global__ __launch_bounds__(256, 4) void attn_kernel(
    const short* __restrict__ Q, const short* __restrict__ K,
    const short* __restrict__ VT, short* __restrict__ CTX)
{
    __shared__ __align__(16) short Kt[64 * 64];       // 8 KB
    __shared__ __align__(16) short Vt[64 * 64];       // 8 KB
    __shared__ __align__(16) short Pl[4][16 * 72];    // 9.2 KB (per-wave P)

    const int h    = blockIdx.x;
    const int pair = blockIdx.y;
    const int b    = blockIdx.z;
    const int tid  = threadIdx.x;
    const int wave = tid >> 6;
    const int lane = tid & 63;
    const int quad = lane >> 4;
    const int l15  = lane & 15;

    const size_t base   = (size_t)b * S_ * D_ + (size_t)h * HD_;
    const size_t vtbase = (size_t)(b * H_ + h) * HD_ * S_;

    const int rowS   = tid >> 3;
    const int colSwz = (((tid & 7) - rowS) & 7) * 8;
    const int keyA = (rowS & 15) * 4 + (rowS >> 4);
    const int keyB = ((rowS + 32) & 15) * 4 + ((rowS + 32) >> 4);

    const int ph0 = ((quad + l15) & 7) * 8;
    const int ph1 = ((quad + 4 + l15) & 7) * 8;

    const int strips[2] = { pair, 31 - pair };

    for (int sp = 0; sp < 2; ++sp) {
        const int st  = strips[sp];
        const int q0w = st * 64 + wave * 16;

        short8 qf[2];
        {
            const short* qrow = Q + base + (size_t)(q0w + l15) * D_ + quad * 8;
            qf[0] = *(const short8*)(qrow);
            qf[1] = *(const short8*)(qrow + 32);
        }

        floatx4 o[4] = {};
        floatx4 lsum = {};

        for (int kt = 0; kt <= st; ++kt) {
            const int kv0 = kt * 64;

            __syncthreads();
            gl_lds16(K + base + (size_t)(kv0 + keyA) * D_ + colSwz, &Kt[tid * 8]);
            gl_lds16(K + base + (size_t)(kv0 + keyB) * D_ + colSwz, &Kt[2048 + tid * 8]);
            gl_lds16(VT + vtbase + (size_t)rowS * S_ + kv0 + colSwz, &Vt[tid * 8]);
            gl_lds16(VT + vtbase + (size_t)(rowS + 32) * S_ + kv0 + colSwz, &Vt[2048 + tid * 8]);
            __syncthreads();

            short8 kf[4][2];
#pragma unroll
            for (int g = 0; g < 4; ++g) {
                kf[g][0] = *(const short8*)&Kt[(16 * g + l15) * 64 + ph0];
                kf[g][1] = *(const short8*)&Kt[(16 * g + l15) * 64 + ph1];
            }

            floatx4 s[4] = {};
#pragma unroll
            for (int g = 0; g < 4; ++g) {
                s[g] = MFMA16(qf[0], kf[g][0], s[g]);
                s[g] = MFMA16(qf[1], kf[g][1], s[g]);
            }

            if (kt < st) {
#pragma unroll
                for (int r = 0; r < 4; ++r) {
                    float p[4];
#pragma unroll
                    for (int g = 0; g < 4; ++g)
                        p[g] = __builtin_amdgcn_exp2f(s[g][r]);
                    lsum[r] += (p[0] + p[1]) + (p[2] + p[3]);
                    uint2 pk;
                    pk.x = __builtin_amdgcn_perm(
                        __float_as_uint(p[1]) + 0x8000u,
                        __float_as_uint(p[0]) + 0x8000u, 0x07060302u);
                    pk.y = __builtin_amdgcn_perm(
                        __float_as_uint(p[3]) + 0x8000u,
                        __float_as_uint(p[2]) + 0x8000u, 0x07060302u);
                    *(uint2*)&Pl[wave][(4 * quad + r) * 72 + 4 * l15] = pk;
                }
            } else {
#pragma unroll
                for (int r = 0; r < 4; ++r) {
                    const int qg = q0w + 4 * quad + r;
                    float p[4];
#pragma unroll
                    for (int g = 0; g < 4; ++g) {
                        const int kg = kv0 + 4 * l15 + g;
                        const float t = (kg <= qg) ? s[g][r] : -INFINITY;
                        p[g] = __builtin_amdgcn_exp2f(t);
                    }
                    lsum[r] += (p[0] + p[1]) + (p[2] + p[3]);
                    uint2 pk;
                    pk.x = __builtin_amdgcn_perm(
                        __float_as_uint(p[1]) + 0x8000u,
                        __float_as_uint(p[0]) + 0x8000u, 0x07060302u);
                    pk.y = __builtin_amdgcn_perm(
                        __float_as_uint(p[3]) + 0x8000u,
                        __float_as_uint(p[2]) + 0x8000u, 0x07060302u);
                    *(uint2*)&Pl[wave][(4 * quad + r) * 72 + 4 * l15] = pk;
                }
            }

            const short8 pf0 = *(const short8*)&Pl[wave][l15 * 72 + quad * 8];
            const short8 pf1 = *(const short8*)&Pl[wave][l15 * 72 + 32 + quad * 8];
#pragma unroll
            for (int nb = 0; nb < 4; ++nb) {
                const short8 vf0 = *(const short8*)&Vt[(nb * 16 + l15) * 64 + ph0];
                const short8 vf1 = *(const short8*)&Vt[(nb * 16 + l15) * 64 + ph1];
                o[nb] = MFMA16(pf0, vf0, o[nb]);
                o[nb] = MFMA16(pf1, vf1, o[nb]);
            }
        }

#pragma unroll
        for (int r = 0; r < 4; ++r) {
            float l = lsum[r];
            l += __shfl_xor(l, 1);
            l += __shfl_xor(l, 2);
            l += __shfl_xor(l, 4);
            l += __shfl_xor(l, 8);
            const float inv = 1.0f / l;
            const int row = q0w + 4 * quad + r;
#pragma unroll
            for (int nb = 0; nb < 4; ++nb)
                CTX[base + (size_t)row * D_ + nb * 16 + l15] = f_to_bf16(o[nb][r] * inv);
        }
    }
}

// ---------------------------------------------------------------------------
extern "C" void kernel_launch(void* const* d_in, const int* in_sizes, int n_in,
                              void* d_out, int out_size, void* d_ws, size_t ws_size,
                              hipStream_t stream) {
    (void)in_sizes; (void)n_in; (void)out_size; (void)ws_size;

    const unsigned int* xraw = (const unsigned int*)d_in[0];
    const void* Wq = d_in[1];
    const void* Wk = d_in[2];
    const void* Wv = d_in[3];
    const void* Wo = d_in[4];

    const size_t NE = (size_t)B_ * S_ * D_;   // 8388608
    const size_t NW = (size_t)D_ * D_;        // 1048576

    // ws layout: [xb: NE][wqkv: 3*NW][wob: NW][q: NE][k: NE][VT: NE]
    char* wsb = (char*)d_ws;
    short* xb   = (short*)wsb;                  wsb += NE * sizeof(short);
    short* wqkv = (short*)wsb;                  wsb += 3 * NW * sizeof(short);
    short* wob  = (short*)wsb;                  wsb += NW * sizeof(short);
    short* q    = (short*)wsb;                  wsb += NE * sizeof(short);
    short* k    = (short*)wsb;                  wsb += NE * sizeof(short);
    short* VT   = (short*)wsb;                  wsb += NE * sizeof(short);
    short* ctx  = xb;

    const int conv_blocks = (int)((NE + 4 * NW) / 8 / 256);  // 6144
    convert_all_kernel<<<conv_blocks, 256, 0, stream>>>(
        (const void*)xraw, Wq, Wk, Wv, Wo, xb, xraw);

    const dim3 qkv_grid(B_ * S_ / 256, 3 * D_ / 256, 1);  // 32 x 12
    gemm_qkv256_kernel<<<qkv_grid, 512, 0, stream>>>(xb, wqkv, q, k, VT);

    const dim3 attn_grid(H_, S_ / 128, B_);  // 16 x 16 x 4
    attn_kernel<<<attn_grid, 256, 0, stream>>>(q, k, VT, ctx);

    const dim3 gemm_grid(B_ * S_ / 128, D_ / 128, 1);  // 64 x 8
    gemm_xwT_kernel<<<gemm_grid, 256, 0, stream>>>(ctx, wob, d_out, xraw);
}

// Round 2
// 234.697 us; speedup vs baseline: 1.0316x; 1.0316x over previous
//
#include <hip/hip_runtime.h>
#include <hip/hip_bf16.h>

// B=4, S=2048, D=1024, H=16, HD=64.
// Input dtype detected inline (fp32 vs bf16); compute pipeline is bf16 MFMA.
#define B_  4
#define S_  2048
#define D_  1024
#define H_  16
#define HD_ 64

using short4_ = __attribute__((ext_vector_type(4))) short;
using short8  = __attribute__((ext_vector_type(8))) short;
using floatx4 = __attribute__((ext_vector_type(4))) float;

#define MFMA16(a, b, c) __builtin_amdgcn_mfma_f32_16x16x32_bf16((a), (b), (c), 0, 0, 0)

// softmax scale folded into Q at QKV-GEMM epilogue: (1/sqrt(64)) * log2(e)
#define QSCALE (0.125f * 1.4426950408889634f)

static __device__ __forceinline__ short f_to_bf16(float f) {
    __hip_bfloat16 h = __float2bfloat16(f);
    short s;
    __builtin_memcpy(&s, &h, 2);
    return s;
}

// async global->LDS, 16B per lane; LDS dst must be wave-uniform base + lane*16.
static __device__ __forceinline__ void gl_lds16(const short* g, short* l) {
    __builtin_amdgcn_global_load_lds(
        (const __attribute__((address_space(1))) void*)g,
        (__attribute__((address_space(3))) void*)l, 16, 0, 0);
}

// Inline dtype detect: lanes 0..63 read x's first 64 dwords as fp32.
static __device__ __forceinline__ bool detect_fp32(const unsigned int* __restrict__ xraw) {
    const float f = __uint_as_float(xraw[threadIdx.x & 63]);
    const bool weird = !(f == f) || fabsf(f) > 1e30f;
    return __ballot(weird) == 0ull;
}

// ---------------------------------------------------------------------------
// Merged convert: virtual concat [x | Wq | Wk | Wv | Wo] -> contiguous
// bf16 [xb | wqkv(3) | wob]. One launch.
// ---------------------------------------------------------------------------
__global__ __launch_bounds__(256) void convert_all_kernel(
    const void* __restrict__ x,  const void* __restrict__ wq,
    const void* __restrict__ wk, const void* __restrict__ wv,
    const void* __restrict__ wo, short* __restrict__ dst,
    const unsigned int* __restrict__ xraw)
{
    const bool isf32 = detect_fp32(xraw);
    const size_t NE = (size_t)B_ * S_ * D_;   // 8388608
    const size_t NW = (size_t)D_ * D_;        // 1048576 = 2^20
    const size_t i = ((size_t)blockIdx.x * 256 + threadIdx.x) * 8;

    const void* src;
    size_t off;
    if (i < NE) { src = x; off = i; }
    else {
        const size_t j = i - NE;
        const int r = (int)(j >> 20);
        src = (r == 0) ? wq : (r == 1) ? wk : (r == 2) ? wv : wo;
        off = j & (NW - 1);
    }

    if (isf32) {
        const float* s = (const float*)src + off;
        short8 o;
#pragma unroll
        for (int j2 = 0; j2 < 8; ++j2) o[j2] = f_to_bf16(s[j2]);
        *(short8*)(dst + i) = o;
    } else {
        *(short8*)(dst + i) = *(const short8*)((const short*)src + off);
    }
}

// ---------------------------------------------------------------------------
// Fused QKV GEMM -- 256x256 tile, 4-phase counted-vmcnt pipeline (T3+T4+T5)
// WITH cross-phase fragment register reuse (24 ds_read_b128 per K-tile per
// wave -- A fragments read once per mh-half, B once per nh-half):
//   P1 (mh0,nh0): read af(mh0) 8x + bf0 4x | stage (t+1).U1 | 16 MFMA
//   P2 (mh0,nh1): read bf1 4x              | stage (t+1).U3 | 16 MFMA
//   P3 (mh1,nh0): read af(mh1) 8x (overwrite af) | stage (t+2).U0 | 16 MFMA
//   P4 (mh1,nh1): no ds_reads              | stage (t+2).U2 | 16 MFMA | gate
// Gate: vmcnt(4) at P4 (2 stage units = 4 loads stay in flight), never 0 in
// steady state.
//
// Stage units (region lifetimes, all overwrites occur >=1 end-barrier after
// the region's last ds_read):
//   U0 = A rows {0-63,128-191}   read P1 -> staged (t+2) at P3
//   U1 = A rows {64-127,192-255} read P3 -> staged (t+1) at P1 (other buffer)
//   U2 = B nh0 prows 0-127       read P1 -> staged (t+2) at P4
//   U3 = B nh1 prows 128-255     read P2 -> staged (t+1) at P2 (other buffer)
// B rows live nh-permuted in LDS (per-lane global src absorbs the perm).
// Rows are 64 bf16 = 8 16B-blocks, XOR-swizzled (phys = (logical+row)&7).
// sel==0 (Q): output pre-scaled by QSCALE.
// sel==2 (V): output written as per-head V^T via LDS transpose epilogue.
// ---------------------------------------------------------------------------
__global__ __launch_bounds__(512, 2) void gemm_qkv256_kernel(
    const short* __restrict__ X, const short* __restrict__ W,
    short* __restrict__ Yq, short* __restrict__ Yk, short* __restrict__ VT)
{
    __shared__ __align__(16) short Lds[65536];   // 128 KiB: 2 buffers x (A 32K + B 32K shorts)

    const int tid  = threadIdx.x;
    const int wave = tid >> 6;
    const int lane = tid & 63;
    const int quad = lane >> 4;
    const int l15  = lane & 15;

    const int mBase = blockIdx.x * 256;
    const int nTot  = blockIdx.y * 256;          // 0..3071
    const int sel   = nTot >> 10;                // 0=q,1=k,2=v

    const int wm   = (wave >> 2) * 128;          // 0 / 128
    const int wn   = (wave & 3) * 64;            // 0,64,128,192
    const int wn32 = (wave & 3) * 32;            // B prow sub-base

    // staging geometry: 8 threads/row, 64 rows per global_load_lds instruction
    const int rS  = tid >> 3;                            // 0..63
    const int sb8 = (((tid & 7) - rS) & 7) * 8;          // swizzled source block

    // A chunk sources (natural row layout): U0={gA0,gA1} U1={gA2,gA3}
    const short* gA0 = X + (size_t)(mBase +   0 + rS) * D_ + sb8;
    const short* gA1 = X + (size_t)(mBase + 128 + rS) * D_ + sb8;
    const short* gA2 = X + (size_t)(mBase +  64 + rS) * D_ + sb8;
    const short* gA3 = X + (size_t)(mBase + 192 + rS) * D_ + sb8;
    // B chunk sources (nh-permuted prow layout): U2={gB0,gB1} U3={gB2,gB3}
    // prow -> logical row: ((prow&127)>>5)*64 + (prow>>7)*32 + (prow&31)
    auto nl = [](int pr) { return ((pr & 127) >> 5) * 64 + (pr >> 7) * 32 + (pr & 31); };
    const short* gB0 = W + (size_t)(nTot + nl(  0 + rS)) * D_ + sb8;
    const short* gB1 = W + (size_t)(nTot + nl( 64 + rS)) * D_ + sb8;
    const short* gB2 = W + (size_t)(nTot + nl(128 + rS)) * D_ + sb8;
    const short* gB3 = W + (size_t)(nTot + nl(192 + rS)) * D_ + sb8;

    floatx4 acc[8][4] = {};

    // ---- prologue: tile0 all units -> buf0; tile1 U0,U2 -> buf1 ------------
    gl_lds16(gA0,      Lds +     0 + tid * 8);   // t0.U0
    gl_lds16(gA1,      Lds +  8192 + tid * 8);
    gl_lds16(gA2,      Lds +  4096 + tid * 8);   // t0.U1
    gl_lds16(gA3,      Lds + 12288 + tid * 8);
    gl_lds16(gB0,      Lds + 16384 + tid * 8);   // t0.U2
    gl_lds16(gB1,      Lds + 20480 + tid * 8);
    gl_lds16(gB2,      Lds + 24576 + tid * 8);   // t0.U3
    gl_lds16(gB3,      Lds + 28672 + tid * 8);
    gl_lds16(gA0 + 64, Lds + 32768 +     0 + tid * 8);   // t1.U0
    gl_lds16(gA1 + 64, Lds + 32768 +  8192 + tid * 8);
    gl_lds16(gB0 + 64, Lds + 32768 + 16384 + tid * 8);   // t1.U2
    gl_lds16(gB1 + 64, Lds + 32768 + 20480 + tid * 8);
    asm volatile("s_waitcnt vmcnt(4)" ::: "memory");     // t0 landed; t1 half in flight
    __builtin_amdgcn_s_barrier();

    // ---- main loop: 16 K-tiles, 4 phases each ------------------------------
#pragma unroll 2
    for (int t = 0; t < 16; ++t) {
        short* pA = Lds + (t & 1) * 32768;
        short* pB = pA + 16384;
        short* qA = Lds + ((t + 1) & 1) * 32768;
        short* qB = qA + 16384;
        const int k1 = (t + 1) * 64;
        const int k2 = (t + 2) * 64;
        const bool s1 = (t + 1) < 16;
        const bool s2 = (t + 2) < 16;

        short8 af[4][2], bf0[2][2], bf1[2][2];

        // ---------------- P1 (mh0, nh0): read af(mh0) + bf0 -----------------
#pragma unroll
        for (int mi = 0; mi < 4; ++mi) {
            const int row = wm + 16 * mi + l15;
#pragma unroll
            for (int ks = 0; ks < 2; ++ks)
                af[mi][ks] = *(const short8*)&pA[row * 64 + ((4 * ks + quad + l15) & 7) * 8];
        }
#pragma unroll
        for (int ni = 0; ni < 2; ++ni) {
            const int prow = wn32 + 16 * ni + l15;
#pragma unroll
            for (int ks = 0; ks < 2; ++ks)
                bf0[ni][ks] = *(const short8*)&pB[prow * 64 + ((4 * ks + quad + l15) & 7) * 8];
        }
        if (s1) { gl_lds16(gA2 + k1, qA +  4096 + tid * 8);     // (t+1).U1
                  gl_lds16(gA3 + k1, qA + 12288 + tid * 8); }
        __builtin_amdgcn_s_barrier();
        asm volatile("s_waitcnt lgkmcnt(0)" ::: "memory");
        __builtin_amdgcn_s_setprio(1);
#pragma unroll
        for (int mi = 0; mi < 4; ++mi)
#pragma unroll
            for (int ni = 0; ni < 2; ++ni)
#pragma unroll
                for (int ks = 0; ks < 2; ++ks)
                    acc[mi][ni] = MFMA16(af[mi][ks], bf0[ni][ks], acc[mi][ni]);
        __builtin_amdgcn_s_setprio(0);
        __builtin_amdgcn_s_barrier();

        // ---------------- P2 (mh0, nh1): read bf1 only ----------------------
#pragma unroll
        for (int ni = 0; ni < 2; ++ni) {
            const int prow = 128 + wn32 + 16 * ni + l15;
#pragma unroll
            for (int ks = 0; ks < 2; ++ks)
                bf1[ni][ks] = *(const short8*)&pB[prow * 64 + ((4 * ks + quad + l15) & 7) * 8];
        }
        if (s1) { gl_lds16(gB2 + k1, qB +  8192 + tid * 8);     // (t+1).U3
                  gl_lds16(gB3 + k1, qB + 12288 + tid * 8); }
        __builtin_amdgcn_s_barrier();
        asm volatile("s_waitcnt lgkmcnt(0)" ::: "memory");
        __builtin_amdgcn_s_setprio(1);
#pragma unroll
        for (int mi = 0; mi < 4; ++mi)
#pragma unroll
            for (int ni = 0; ni < 2; ++ni)
#pragma unroll
                for (int ks = 0; ks < 2; ++ks)
                    acc[mi][2 + ni] = MFMA16(af[mi][ks], bf1[ni][ks], acc[mi][2 + ni]);
        __builtin_amdgcn_s_setprio(0);
        __builtin_amdgcn_s_barrier();

        // ---------------- P3 (mh1, nh0): read af(mh1), reuse bf0 ------------
#pragma unroll
        for (int mi = 0; mi < 4; ++mi) {
            const int row = wm + 64 + 16 * mi + l15;
#pragma unroll
            for (int ks = 0; ks < 2; ++ks)
                af[mi][ks] = *(const short8*)&pA[row * 64 + ((4 * ks + quad + l15) & 7) * 8];
        }
        if (s2) { gl_lds16(gA0 + k2, pA +        tid * 8);      // (t+2).U0 (U0 free since P2)
                  gl_lds16(gA1 + k2, pA +  8192 + tid * 8); }
        __builtin_amdgcn_s_barrier();
        asm volatile("s_waitcnt lgkmcnt(0)" ::: "memory");
        __builtin_amdgcn_s_setprio(1);
#pragma unroll
        for (int mi = 0; mi < 4; ++mi)
#pragma unroll
            for (int ni = 0; ni < 2; ++ni)
#pragma unroll
                for (int ks = 0; ks < 2; ++ks)
                    acc[4 + mi][ni] = MFMA16(af[mi][ks], bf0[ni][ks], acc[4 + mi][ni]);
        __builtin_amdgcn_s_setprio(0);
        __builtin_amdgcn_s_barrier();

        // ---------------- P4 (mh1, nh1): no ds_reads, reuse af + bf1 --------
        if (s2) { gl_lds16(gB0 + k2, pB +        tid * 8);      // (t+2).U2 (U2 free since P2)
                  gl_lds16(gB1 + k2, pB +  4096 + tid * 8); }
        __builtin_amdgcn_s_barrier();
        __builtin_amdgcn_s_setprio(1);
#pragma unroll
        for (int mi = 0; mi < 4; ++mi)
#pragma unroll
            for (int ni = 0; ni < 2; ++ni)
#pragma unroll
                for (int ks = 0; ks < 2; ++ks)
                    acc[4 + mi][2 + ni] = MFMA16(af[mi][ks], bf1[ni][ks], acc[4 + mi][2 + ni]);
        __builtin_amdgcn_s_setprio(0);
        if (s2) asm volatile("s_waitcnt vmcnt(4)" ::: "memory");
        else    asm volatile("s_waitcnt vmcnt(0)" ::: "memory");
        __builtin_amdgcn_s_barrier();
    }

    // ---- epilogue ----------------------------------------------------------
    if (sel < 2) {
        short* Y = (sel == 0) ? Yq : Yk;
        const float osc = (sel == 0) ? QSCALE : 1.0f;
        const int nBase = nTot & 1023;
#pragma unroll
        for (int mh = 0; mh < 2; ++mh)
#pragma unroll
        for (int mi = 0; mi < 4; ++mi)
#pragma unroll
        for (int nh = 0; nh < 2; ++nh)
#pragma unroll
        for (int ni = 0; ni < 2; ++ni)
#pragma unroll
        for (int r = 0; r < 4; ++r) {
            const size_t idx =
                (size_t)(mBase + wm + mh * 64 + 16 * mi + 4 * quad + r) * D_ +
                (nBase + wn + nh * 32 + 16 * ni + l15);
            Y[idx] = f_to_bf16(acc[mh * 4 + mi][nh * 2 + ni][r] * osc);
        }
    } else {
        // V^T epilogue: LDS transpose (Tb = 128 chans x 256 m, stride 264),
        // two halves of 128 channels; coalesced 512B-row writes to VT.
        const int bb = mBase >> 11;     // batch
        const int s0 = mBase & 2047;    // seq base
        const int nBase = nTot & 1023;
        short* Tb = Lds;
        const int myhalf = wn >> 7;
#pragma unroll
        for (int half = 0; half < 2; ++half) {
            __syncthreads();  // LDS free (k-loop drained / previous half read)
            if (myhalf == half) {
#pragma unroll
                for (int nh = 0; nh < 2; ++nh)
#pragma unroll
                for (int ni = 0; ni < 2; ++ni)
#pragma unroll
                for (int mh = 0; mh < 2; ++mh)
#pragma unroll
                for (int mi = 0; mi < 4; ++mi) {
                    short4_ v4;
#pragma unroll
                    for (int r = 0; r < 4; ++r)
                        v4[r] = f_to_bf16(acc[mh * 4 + mi][nh * 2 + ni][r]);
                    const int cl = (wn & 64) + nh * 32 + 16 * ni + l15;
                    *(short4_*)&Tb[cl * 264 + wm + mh * 64 + 16 * mi + 4 * quad] = v4;
                }
            }
            __syncthreads();
#pragma unroll
            for (int p = 0; p < 8; ++p) {
                const int t2 = tid + p * 512;
                const int cl = t2 >> 5;           // 0..127
                const int mc = (t2 & 31) * 8;     // 0..248
                const short8 val = *(const short8*)&Tb[cl * 264 + mc];
                const int c  = nBase + half * 128 + cl;   // global channel
                const int hh = c >> 6, hd = c & 63;
                *(short8*)&VT[((size_t)(bb * H_ + hh) * HD_ + hd) * S_ + s0 + mc] = val;
            }
        }
    }
}

// ---------------------------------------------------------------------------
// GEMM: Y = X @ W^T, BK=64 (used for the Wo projection). fp32 out if input
// dtype (detected from xraw) is fp32.
// ---------------------------------------------------------------------------
__global__ __launch_bounds__(256) void gemm_xwT_kernel(
    const short* __restrict__ X, const short* __restrict__ W,
    void* __restrict__ Y, const unsigned int* __restrict__ xraw)
{
    __shared__ __align__(16) short LDS[2 * 128 * 64];
    short* Atile = LDS;
    short* Btile = LDS + 128 * 64;

    const bool f32out = detect_fp32(xraw);

    const int tid  = threadIdx.x;
    const int wave = tid >> 6;
    const int lane = tid & 63;
    const int quad = lane >> 4;
    const int l15  = lane & 15;

    const int mBase = blockIdx.x * 128;
    const int nBase = blockIdx.y * 128;
    const int wm = (wave & 1) * 64;
    const int wn = (wave >> 1) * 64;

    const int rowS = tid >> 3;
    const int colS = (((tid & 7) - rowS) & 7) * 8;
    const short* gA = X + (size_t)(mBase + rowS) * D_ + colS;
    const short* gB = W + (size_t)(nBase + rowS) * D_ + colS;

    floatx4 acc[4][4] = {};

    for (int k0 = 0; k0 < D_; k0 += 64) {
#pragma unroll
        for (int p = 0; p < 4; ++p) {
            gl_lds16(gA + (size_t)(p * 32) * D_ + k0, &Atile[p * 2048 + tid * 8]);
            gl_lds16(gB + (size_t)(p * 32) * D_ + k0, &Btile[p * 2048 + tid * 8]);
        }
        __syncthreads();

#pragma unroll
        for (int ks = 0; ks < 2; ++ks) {
            const int pblk = ((4 * ks + quad + l15) & 7) * 8;
            short8 a[4], b[4];
#pragma unroll
            for (int i = 0; i < 4; ++i) {
                a[i] = *(const short8*)&Atile[(wm + 16 * i + l15) * 64 + pblk];
                b[i] = *(const short8*)&Btile[(wn + 16 * i + l15) * 64 + pblk];
            }
#pragma unroll
            for (int mi = 0; mi < 4; ++mi)
#pragma unroll
                for (int ni = 0; ni < 4; ++ni)
                    acc[mi][ni] = MFMA16(a[mi], b[ni], acc[mi][ni]);
        }
        __syncthreads();
    }

#pragma unroll
    for (int mi = 0; mi < 4; ++mi)
#pragma unroll
        for (int ni = 0; ni < 4; ++ni)
#pragma unroll
            for (int r = 0; r < 4; ++r) {
                const size_t idx =
                    (size_t)(mBase + wm + 16 * mi + quad * 4 + r) * D_ +
                    (nBase + wn + 16 * ni + l15);
                if (f32out) ((float*)Y)[idx] = acc[mi][ni][r];
                else        ((short*)Y)[idx] = f_to_bf16(acc[mi][ni][r]);
            }
}

// ---------------------------------------------------------------------------
// Flash attention, causal. Strips of 64 queries; block handles pair
// {j, 31-j} sequentially -> exactly 33 k-rounds/block (balanced).
// grid = (H, 16 pairs, B): same-(b,h) blocks are 16 apart in linear order
// -> same XCD -> K/VT L2-resident. 1024 blocks = 4/CU (launch_bounds 256,4).
// ---------------------------------------------------------------------------
__global__ __launch_bounds__(256, 4) void attn_kernel(
    const short* __restrict__ Q, const short* __restrict__ K,
    const short* __restrict__ VT, short* __restrict__ CTX)
{
    __shared__ __align__(16) short Kt[64 * 64];       // 8 KB
    __shared__ __align__(16) short Vt[64 * 64];       // 8 KB
    __shared__ __align__(16) short Pl[4][16 * 72];    // 9.2 KB (per-wave P)

    const int h    = blockIdx.x;
    const int pair = blockIdx.y;
    const int b    = blockIdx.z;
    const int tid  = threadIdx.x;
    const int wave = tid >> 6;
    const int lane = tid & 63;
    const int quad = lane >> 4;
    const int l15  = lane & 15;

    const size_t base   = (size_t)b * S_ * D_ + (size_t)h * HD_;
    const size_t vtbase = (size_t)(b * H_ + h) * HD_ * S_;

    const int rowS   = tid >> 3;
    const int colSwz = (((tid & 7) - rowS) & 7) * 8;
    const int keyA = (rowS & 15) * 4 + (rowS >> 4);
    const int keyB = ((rowS + 32) & 15) * 4 + ((rowS + 32) >> 4);

    const int ph0 = ((quad + l15) & 7) * 8;
    const int ph1 = ((quad + 4 + l15) & 7) * 8;

    const int strips[2] = { pair, 31 - pair };

    for (int sp = 0; sp < 2; ++sp) {
        const int st  = strips[sp];
        const int q0w = st * 64 + wave * 16;

        short8 qf[2];
        {
            const short* qrow = Q + base + (size_t)(q0w + l15) * D_ + quad * 8;
            qf[0] = *(const short8*)(qrow);
            qf[1] = *(const short8*)(qrow + 32);
        }

        floatx4 o[4] = {};
        floatx4 lsum = {};

        for (int kt = 0; kt <= st; ++kt) {
            const int kv0 = kt * 64;

            __syncthreads();
            gl_lds16(K + base + (size_t)(kv0 + keyA) * D_ + colSwz, &Kt[tid * 8]);
            gl_lds16(K + base + (size_t)(kv0 + keyB) * D_ + colSwz, &Kt[2048 + tid * 8]);
            gl_lds16(VT + vtbase + (size_t)rowS * S_ + kv0 + colSwz, &Vt[tid * 8]);
            gl_lds16(VT + vtbase + (size_t)(rowS + 32) * S_ + kv0 + colSwz, &Vt[2048 + tid * 8]);
            __syncthreads();

            short8 kf[4][2];
#pragma unroll
            for (int g = 0; g < 4; ++g) {
                kf[g][0] = *(const short8*)&Kt[(16 * g + l15) * 64 + ph0];
                kf[g][1] = *(const short8*)&Kt[(16 * g + l15) * 64 + ph1];
            }

            floatx4 s[4] = {};
#pragma unroll
            for (int g = 0; g < 4; ++g) {
                s[g] = MFMA16(qf[0], kf[g][0], s[g]);
                s[g] = MFMA16(qf[1], kf[g][1], s[g]);
            }

            if (kt < st) {
#pragma unroll
                for (int r = 0; r < 4; ++r) {
                    float p[4];
#pragma unroll
                    for (int g = 0; g < 4; ++g)
                        p[g] = __builtin_amdgcn_exp2f(s[g][r]);
                    lsum[r] += (p[0] + p[1]) + (p[2] + p[3]);
                    uint2 pk;
                    pk.x = __builtin_amdgcn_perm(
                        __float_as_uint(p[1]) + 0x8000u,
                        __float_as_uint(p[0]) + 0x8000u, 0x07060302u);
                    pk.y = __builtin_amdgcn_perm(
                        __float_as_uint(p[3]) + 0x8000u,
                        __float_as_uint(p[2]) + 0x8000u, 0x07060302u);
                    *(uint2*)&Pl[wave][(4 * quad + r) * 72 + 4 * l15] = pk;
                }
            } else {
#pragma unroll
                for (int r = 0; r < 4; ++r) {
                    const int qg = q0w + 4 * quad + r;
                    float p[4];
#pragma unroll
                    for (int g = 0; g < 4; ++g) {
                        const int kg = kv0 + 4 * l15 + g;
                        const float t = (kg <= qg) ? s[g][r] : -INFINITY;
                        p[g] = __builtin_amdgcn_exp2f(t);
                    }
                    lsum[r] += (p[0] + p[1]) + (p[2] + p[3]);
                    uint2 pk;
                    pk.x = __builtin_amdgcn_perm(
                        __float_as_uint(p[1]) + 0x8000u,
                        __float_as_uint(p[0]) + 0x8000u, 0x07060302u);
                    pk.y = __builtin_amdgcn_perm(
                        __float_as_uint(p[3]) + 0x8000u,
                        __float_as_uint(p[2]) + 0x8000u, 0x07060302u);
                    *(uint2*)&Pl[wave][(4 * quad + r) * 72 + 4 * l15] = pk;
                }
            }

            const short8 pf0 = *(const short8*)&Pl[wave][l15 * 72 + quad * 8];
            const short8 pf1 = *(const short8*)&Pl[wave][l15 * 72 + 32 + quad * 8];
#pragma unroll
            for (int nb = 0; nb < 4; ++nb) {
                const short8 vf0 = *(const short8*)&Vt[(nb * 16 + l15) * 64 + ph0];
                const short8 vf1 = *(const short8*)&Vt[(nb * 16 + l15) * 64 + ph1];
                o[nb] = MFMA16(pf0, vf0, o[nb]);
                o[nb] = MFMA16(pf1, vf1, o[nb]);
            }
        }

#pragma unroll
        for (int r = 0; r < 4; ++r) {
            float l = lsum[r];
            l += __shfl_xor(l, 1);
            l += __shfl_xor(l, 2);
            l += __shfl_xor(l, 4);
            l += __shfl_xor(l, 8);
            const float inv = 1.0f / l;
            const int row = q0w + 4 * quad + r;
#pragma unroll
            for (int nb = 0; nb < 4; ++nb)
                CTX[base + (size_t)row * D_ + nb * 16 + l15] = f_to_bf16(o[nb][r] * inv);
        }
    }
}

// ---------------------------------------------------------------------------
extern "C" void kernel_launch(void* const* d_in, const int* in_sizes, int n_in,
                              void* d_out, int out_size, void* d_ws, size_t ws_size,
                              hipStream_t stream) {
    (void)in_sizes; (void)n_in; (void)out_size; (void)ws_size;

    const unsigned int* xraw = (const unsigned int*)d_in[0];
    const void* Wq = d_in[1];
    const void* Wk = d_in[2];
    const void* Wv = d_in[3];
    const void* Wo = d_in[4];

    const size_t NE = (size_t)B_ * S_ * D_;   // 8388608
    const size_t NW = (size_t)D_ * D_;        // 1048576

    // ws layout: [xb: NE][wqkv: 3*NW][wob: NW][q: NE][k: NE][VT: NE]
    char* wsb = (char*)d_ws;
    short* xb   = (short*)wsb;                  wsb += NE * sizeof(short);
    short* wqkv = (short*)wsb;                  wsb += 3 * NW * sizeof(short);
    short* wob  = (short*)wsb;                  wsb += NW * sizeof(short);
    short* q    = (short*)wsb;                  wsb += NE * sizeof(short);
    short* k    = (short*)wsb;                  wsb += NE * sizeof(short);
    short* VT   = (short*)wsb;                  wsb += NE * sizeof(short);
    short* ctx  = xb;

    const int conv_blocks = (int)((NE + 4 * NW) / 8 / 256);  // 6144
    convert_all_kernel<<<conv_blocks, 256, 0, stream>>>(
        (const void*)xraw, Wq, Wk, Wv, Wo, xb, xraw);

    const dim3 qkv_grid(B_ * S_ / 256, 3 * D_ / 256, 1);  // 32 x 12
    gemm_qkv256_kernel<<<qkv_grid, 512, 0, stream>>>(xb, wqkv, q, k, VT);

    const dim3 attn_grid(H_, S_ / 128, B_);  // 16 x 16 x 4
    attn_kernel<<<attn_grid, 256, 0, stream>>>(q, k, VT, ctx);

    const dim3 gemm_grid(B_ * S_ / 128, D_ / 128, 1);  // 64 x 8
    gemm_xwT_kernel<<<gemm_grid, 256, 0, stream>>>(ctx, wob, d_out, xraw);
}

// Round 4
// 224.204 us; speedup vs baseline: 1.0799x; 1.0468x over previous
//
#include <hip/hip_runtime.h>
#include <hip/hip_bf16.h>

// B=4, S=2048, D=1024, H=16, HD=64.
// Input dtype detected inline (fp32 vs bf16); compute pipeline is bf16 MFMA.
#define B_  4
#define S_  2048
#define D_  1024
#define H_  16
#define HD_ 64

using short4_ = __attribute__((ext_vector_type(4))) short;
using short8  = __attribute__((ext_vector_type(8))) short;
using floatx4 = __attribute__((ext_vector_type(4))) float;

#define MFMA16(a, b, c) __builtin_amdgcn_mfma_f32_16x16x32_bf16((a), (b), (c), 0, 0, 0)

// softmax scale folded into Q at QKV-GEMM epilogue: (1/sqrt(64)) * log2(e)
#define QSCALE (0.125f * 1.4426950408889634f)

static __device__ __forceinline__ short f_to_bf16(float f) {
    __hip_bfloat16 h = __float2bfloat16(f);
    short s;
    __builtin_memcpy(&s, &h, 2);
    return s;
}

// async global->LDS, 16B per lane; LDS dst must be wave-uniform base + lane*16.
static __device__ __forceinline__ void gl_lds16(const short* g, short* l) {
    __builtin_amdgcn_global_load_lds(
        (const __attribute__((address_space(1))) void*)g,
        (__attribute__((address_space(3))) void*)l, 16, 0, 0);
}

// Inline dtype detect: lanes 0..63 read x's first 64 dwords as fp32.
static __device__ __forceinline__ bool detect_fp32(const unsigned int* __restrict__ xraw) {
    const float f = __uint_as_float(xraw[threadIdx.x & 63]);
    const bool weird = !(f == f) || fabsf(f) > 1e30f;
    return __ballot(weird) == 0ull;
}

// ---------------------------------------------------------------------------
// Merged convert: virtual concat [x | Wq | Wk | Wv | Wo] -> contiguous
// bf16 [xb | wqkv(3) | wob]. One launch.
// ---------------------------------------------------------------------------
__global__ __launch_bounds__(256) void convert_all_kernel(
    const void* __restrict__ x,  const void* __restrict__ wq,
    const void* __restrict__ wk, const void* __restrict__ wv,
    const void* __restrict__ wo, short* __restrict__ dst,
    const unsigned int* __restrict__ xraw)
{
    const bool isf32 = detect_fp32(xraw);
    const size_t NE = (size_t)B_ * S_ * D_;   // 8388608
    const size_t NW = (size_t)D_ * D_;        // 1048576 = 2^20
    const size_t i = ((size_t)blockIdx.x * 256 + threadIdx.x) * 8;

    const void* src;
    size_t off;
    if (i < NE) { src = x; off = i; }
    else {
        const size_t j = i - NE;
        const int r = (int)(j >> 20);
        src = (r == 0) ? wq : (r == 1) ? wk : (r == 2) ? wv : wo;
        off = j & (NW - 1);
    }

    if (isf32) {
        const float* s = (const float*)src + off;
        short8 o;
#pragma unroll
        for (int j2 = 0; j2 < 8; ++j2) o[j2] = f_to_bf16(s[j2]);
        *(short8*)(dst + i) = o;
    } else {
        *(short8*)(dst + i) = *(const short8*)((const short*)src + off);
    }
}

// ---------------------------------------------------------------------------
// 256x128-tile pipelined GEMM core, shared by qkv and xwT kernels.
// 512 thr / 8 waves; wave = 64x64 (acc[4][4], 64 VGPR). BK=64.
// LDS: 2 buffers x (A 32KB + B 16KB) = 96 KiB. Register fragments are ALSO
// double-buffered (afA/bfA vs afB/bfB, 128 VGPR) so the frag ds_reads of
// tile t+1 drain UNDER the MFMA block of tile t (LDS 1024cyc < MFMA 1242cyc
// per CU) -- no lockstep serialization of LDS reads vs MFMA.
// Per K-tile: 2 barriers only; counted vmcnt(6) gate (2 tiles of staging in
// flight, never drained to 0 mid-loop).
//   body(t): lgkm(0)            // frags(t) (read last body) landed -> buf[cur] free
//            barrier            // all waves done with buf[cur]
//            STAGE t+2 -> buf[cur]  (6 gl_lds16)
//            vmcnt(6); barrier  // t+1 landed & visible
//            READ_FRAGS t+1 <- buf[cur^1] into alternate frag set (async)
//            32 MFMA on current frag set (setprio-wrapped)
// Rows are 64 bf16 = 8 16B-blocks, XOR-swizzled (phys = (logical+row)&7),
// applied via pre-swizzled global source column (sb8).
// ---------------------------------------------------------------------------
#define STAGE6(BUF, KO)                                                         \
  { const short* a0_ = gA + (KO);                                               \
    gl_lds16(a0_,            (BUF) +     0 + tid * 8);                          \
    gl_lds16(a0_ +  64 * D_, (BUF) +  4096 + tid * 8);                          \
    gl_lds16(a0_ + 128 * D_, (BUF) +  8192 + tid * 8);                          \
    gl_lds16(a0_ + 192 * D_, (BUF) + 12288 + tid * 8);                          \
    const short* b0_ = gB + (KO);                                               \
    gl_lds16(b0_,            (BUF) + 16384 + tid * 8);                          \
    gl_lds16(b0_ +  64 * D_, (BUF) + 20480 + tid * 8); }

#define READ_FRAGS(AF, BF, BUF)                                                 \
  { _Pragma("unroll")                                                           \
    for (int mi = 0; mi < 4; ++mi) {                                            \
      AF[mi][0] = *(const short8*)&(BUF)[(wm + 16*mi + l15) * 64 + ((    quad + l15) & 7) * 8]; \
      AF[mi][1] = *(const short8*)&(BUF)[(wm + 16*mi + l15) * 64 + ((4 + quad + l15) & 7) * 8]; \
    }                                                                           \
    _Pragma("unroll")                                                           \
    for (int ni = 0; ni < 4; ++ni) {                                            \
      BF[ni][0] = *(const short8*)&(BUF)[16384 + (wn + 16*ni + l15) * 64 + ((    quad + l15) & 7) * 8]; \
      BF[ni][1] = *(const short8*)&(BUF)[16384 + (wn + 16*ni + l15) * 64 + ((4 + quad + l15) & 7) * 8]; \
    } }

#define DO_MFMA(AF, BF)                                                         \
  { __builtin_amdgcn_s_setprio(1);                                              \
    _Pragma("unroll")                                                           \
    for (int mi = 0; mi < 4; ++mi)                                              \
      _Pragma("unroll")                                                         \
      for (int ni = 0; ni < 4; ++ni) {                                          \
        acc[mi][ni] = MFMA16(AF[mi][0], BF[ni][0], acc[mi][ni]);                \
        acc[mi][ni] = MFMA16(AF[mi][1], BF[ni][1], acc[mi][ni]);                \
      }                                                                         \
    __builtin_amdgcn_s_setprio(0); }

#define GEMM_BODY(CURB, NXTB, AF_U, BF_U, AF_F, BF_F, KO2, S1, S2)              \
  {                                                                             \
    asm volatile("s_waitcnt lgkmcnt(0)" ::: "memory");                          \
    __builtin_amdgcn_s_barrier();                                               \
    if (S2) STAGE6(CURB, KO2)                                                   \
    if (S2) { asm volatile("s_waitcnt vmcnt(6)" ::: "memory"); }                \
    else    { asm volatile("s_waitcnt vmcnt(0)" ::: "memory"); }                \
    __builtin_amdgcn_s_barrier();                                               \
    if (S1) READ_FRAGS(AF_F, BF_F, NXTB)                                        \
    DO_MFMA(AF_U, BF_U)                                                         \
  }

#define GEMM_PREAMBLE                                                           \
    const int tid  = threadIdx.x;                                               \
    const int wave = tid >> 6;                                                  \
    const int lane = tid & 63;                                                  \
    const int quad = lane >> 4;                                                 \
    const int l15  = lane & 15;                                                 \
    const int wm   = (wave >> 1) * 64;                                          \
    const int wn   = (wave & 1) * 64;                                           \
    const int rS   = tid >> 3;                                                  \
    const int sb8  = (((tid & 7) - rS) & 7) * 8;                                \
    short* const buf0 = Lds;                                                    \
    short* const buf1 = Lds + 24576;                                            \
    short8 afA[4][2], bfA[4][2], afB[4][2], bfB[4][2];                          \
    floatx4 acc[4][4] = {};

#define GEMM_KLOOP                                                              \
    STAGE6(buf0, 0)                                                             \
    STAGE6(buf1, 64)                                                            \
    asm volatile("s_waitcnt vmcnt(6)" ::: "memory");                            \
    __builtin_amdgcn_s_barrier();                                               \
    READ_FRAGS(afA, bfA, buf0)                                                  \
    int ko = 128;                                                               \
    for (int it = 0; it < 7; ++it) {                                            \
        GEMM_BODY(buf0, buf1, afA, bfA, afB, bfB, ko,      true, true)          \
        GEMM_BODY(buf1, buf0, afB, bfB, afA, bfA, ko + 64, true, true)          \
        ko += 128;                                                              \
    }                                                                           \
    GEMM_BODY(buf0, buf1, afA, bfA, afB, bfB, 0, true,  false)  /* t=14 */      \
    GEMM_BODY(buf1, buf0, afB, bfB, afA, bfA, 0, false, false)  /* t=15 */

// ---------------------------------------------------------------------------
// Fused QKV GEMM. W = concat(Wq,Wk,Wv) rows [3072][1024]. Grid 32 x 24 =
// 768 blocks = exactly 3 full rounds on 256 CUs (zero tail waste).
// sel==0 (Q): output pre-scaled by QSCALE.
// sel==2 (V): output written as per-head V^T via LDS transpose epilogue.
// ---------------------------------------------------------------------------
__global__ __launch_bounds__(512, 2) void gemm_qkv256_kernel(
    const short* __restrict__ X, const short* __restrict__ W,
    short* __restrict__ Yq, short* __restrict__ Yk, short* __restrict__ VT)
{
    __shared__ __align__(16) short Lds[49152];   // 96 KiB

    GEMM_PREAMBLE

    const int mBase = blockIdx.x * 256;
    const int nTot  = blockIdx.y * 128;          // 0..2943
    const int sel   = nTot >> 10;                // 0=q,1=k,2=v
    const int nBase = nTot & 1023;

    const short* gA = X + (size_t)(mBase + rS) * D_ + sb8;
    const short* gB = W + (size_t)(nTot  + rS) * D_ + sb8;

    GEMM_KLOOP

    if (sel < 2) {
        short* Y = (sel == 0) ? Yq : Yk;
        const float osc = (sel == 0) ? QSCALE : 1.0f;
#pragma unroll
        for (int mi = 0; mi < 4; ++mi)
#pragma unroll
        for (int ni = 0; ni < 4; ++ni)
#pragma unroll
        for (int r = 0; r < 4; ++r) {
            const size_t idx =
                (size_t)(mBase + wm + 16 * mi + 4 * quad + r) * D_ +
                (nBase + wn + 16 * ni + l15);
            Y[idx] = f_to_bf16(acc[mi][ni][r] * osc);
        }
    } else {
        // V^T epilogue: LDS transpose (Tb = 128 chans x 256 m, stride 264),
        // coalesced 512B-row writes to VT.
        const int bb = mBase >> 11;     // batch
        const int s0 = mBase & 2047;    // seq base
        short* Tb = Lds;
        __syncthreads();   // k-loop fully drained; LDS free
#pragma unroll
        for (int ni = 0; ni < 4; ++ni)
#pragma unroll
        for (int mi = 0; mi < 4; ++mi) {
            short4_ v4;
#pragma unroll
            for (int r = 0; r < 4; ++r) v4[r] = f_to_bf16(acc[mi][ni][r]);
            *(short4_*)&Tb[(wn + 16 * ni + l15) * 264 + wm + 16 * mi + 4 * quad] = v4;
        }
        __syncthreads();
#pragma unroll
        for (int p = 0; p < 8; ++p) {
            const int t2 = tid + p * 512;
            const int cl = t2 >> 5;           // 0..127
            const int mc = (t2 & 31) * 8;     // 0..248
            const short8 val = *(const short8*)&Tb[cl * 264 + mc];
            const int c  = nBase + cl;        // global channel
            const int hh = c >> 6, hd = c & 63;
            *(short8*)&VT[((size_t)(bb * H_ + hh) * HD_ + hd) * S_ + s0 + mc] = val;
        }
    }
}

// ---------------------------------------------------------------------------
// Wo projection: Y = ctx @ Wo^T. Grid 32 x 8 = 256 blocks = exactly 1 round.
// fp32 out if input dtype (detected from xraw) is fp32.
// ---------------------------------------------------------------------------
__global__ __launch_bounds__(512, 2) void gemm_xwT_kernel(
    const short* __restrict__ X, const short* __restrict__ W,
    void* __restrict__ Y, const unsigned int* __restrict__ xraw)
{
    __shared__ __align__(16) short Lds[49152];   // 96 KiB

    const bool f32out = detect_fp32(xraw);

    GEMM_PREAMBLE

    const int mBase = blockIdx.x * 256;
    const int nBase = blockIdx.y * 128;

    const short* gA = X + (size_t)(mBase + rS) * D_ + sb8;
    const short* gB = W + (size_t)(nBase + rS) * D_ + sb8;

    GEMM_KLOOP

#pragma unroll
    for (int mi = 0; mi < 4; ++mi)
#pragma unroll
    for (int ni = 0; ni < 4; ++ni)
#pragma unroll
    for (int r = 0; r < 4; ++r) {
        const size_t idx =
            (size_t)(mBase + wm + 16 * mi + 4 * quad + r) * D_ +
            (nBase + wn + 16 * ni + l15);
        if (f32out) ((float*)Y)[idx] = acc[mi][ni][r];
        else        ((short*)Y)[idx] = f_to_bf16(acc[mi][ni][r]);
    }
}

// ---------------------------------------------------------------------------
// Flash attention, causal. Strips of 64 queries; block handles pair
// {j, 31-j} sequentially -> exactly 33 k-rounds/block (balanced).
// grid = (H, 16 pairs, B): same-(b,h) blocks are 16 apart in linear order
// -> same XCD -> K/VT L2-resident. 1024 blocks = 4/CU (launch_bounds 256,4).
// ---------------------------------------------------------------------------
__global__ __launch_bounds__(256, 4) void attn_kernel(
    const short* __restrict__ Q, const short* __restrict__ K,
    const short* __restrict__ VT, short* __restrict__ CTX)
{
    __shared__ __align__(16) short Kt[64 * 64];       // 8 KB
    __shared__ __align__(16) short Vt[64 * 64];       // 8 KB
    __shared__ __align__(16) short Pl[4][16 * 72];    // 9.2 KB (per-wave P)

    const int h    = blockIdx.x;
    const int pair = blockIdx.y;
    const int b    = blockIdx.z;
    const int tid  = threadIdx.x;
    const int wave = tid >> 6;
    const int lane = tid & 63;
    const int quad = lane >> 4;
    const int l15  = lane & 15;

    const size_t base   = (size_t)b * S_ * D_ + (size_t)h * HD_;
    const size_t vtbase = (size_t)(b * H_ + h) * HD_ * S_;

    const int rowS   = tid >> 3;
    const int colSwz = (((tid & 7) - rowS) & 7) * 8;
    const int keyA = (rowS & 15) * 4 + (rowS >> 4);
    const int keyB = ((rowS + 32) & 15) * 4 + ((rowS + 32) >> 4);

    const int ph0 = ((quad + l15) & 7) * 8;
    const int ph1 = ((quad + 4 + l15) & 7) * 8;

    const int strips[2] = { pair, 31 - pair };

    for (int sp = 0; sp < 2; ++sp) {
        const int st  = strips[sp];
        const int q0w = st * 64 + wave * 16;

        short8 qf[2];
        {
            const short* qrow = Q + base + (size_t)(q0w + l15) * D_ + quad * 8;
            qf[0] = *(const short8*)(qrow);
            qf[1] = *(const short8*)(qrow + 32);
        }

        floatx4 o[4] = {};
        floatx4 lsum = {};

        for (int kt = 0; kt <= st; ++kt) {
            const int kv0 = kt * 64;

            __syncthreads();
            gl_lds16(K + base + (size_t)(kv0 + keyA) * D_ + colSwz, &Kt[tid * 8]);
            gl_lds16(K + base + (size_t)(kv0 + keyB) * D_ + colSwz, &Kt[2048 + tid * 8]);
            gl_lds16(VT + vtbase + (size_t)rowS * S_ + kv0 + colSwz, &Vt[tid * 8]);
            gl_lds16(VT + vtbase + (size_t)(rowS + 32) * S_ + kv0 + colSwz, &Vt[2048 + tid * 8]);
            __syncthreads();

            short8 kf[4][2];
#pragma unroll
            for (int g = 0; g < 4; ++g) {
                kf[g][0] = *(const short8*)&Kt[(16 * g + l15) * 64 + ph0];
                kf[g][1] = *(const short8*)&Kt[(16 * g + l15) * 64 + ph1];
            }

            floatx4 s[4] = {};
#pragma unroll
            for (int g = 0; g < 4; ++g) {
                s[g] = MFMA16(qf[0], kf[g][0], s[g]);
                s[g] = MFMA16(qf[1], kf[g][1], s[g]);
            }

            if (kt < st) {
#pragma unroll
                for (int r = 0; r < 4; ++r) {
                    float p[4];
#pragma unroll
                    for (int g = 0; g < 4; ++g)
                        p[g] = __builtin_amdgcn_exp2f(s[g][r]);
                    lsum[r] += (p[0] + p[1]) + (p[2] + p[3]);
                    uint2 pk;
                    pk.x = __builtin_amdgcn_perm(
                        __float_as_uint(p[1]) + 0x8000u,
                        __float_as_uint(p[0]) + 0x8000u, 0x07060302u);
                    pk.y = __builtin_amdgcn_perm(
                        __float_as_uint(p[3]) + 0x8000u,
                        __float_as_uint(p[2]) + 0x8000u, 0x07060302u);
                    *(uint2*)&Pl[wave][(4 * quad + r) * 72 + 4 * l15] = pk;
                }
            } else {
#pragma unroll
                for (int r = 0; r < 4; ++r) {
                    const int qg = q0w + 4 * quad + r;
                    float p[4];
#pragma unroll
                    for (int g = 0; g < 4; ++g) {
                        const int kg = kv0 + 4 * l15 + g;
                        const float t = (kg <= qg) ? s[g][r] : -INFINITY;
                        p[g] = __builtin_amdgcn_exp2f(t);
                    }
                    lsum[r] += (p[0] + p[1]) + (p[2] + p[3]);
                    uint2 pk;
                    pk.x = __builtin_amdgcn_perm(
                        __float_as_uint(p[1]) + 0x8000u,
                        __float_as_uint(p[0]) + 0x8000u, 0x07060302u);
                    pk.y = __builtin_amdgcn_perm(
                        __float_as_uint(p[3]) + 0x8000u,
                        __float_as_uint(p[2]) + 0x8000u, 0x07060302u);
                    *(uint2*)&Pl[wave][(4 * quad + r) * 72 + 4 * l15] = pk;
                }
            }

            const short8 pf0 = *(const short8*)&Pl[wave][l15 * 72 + quad * 8];
            const short8 pf1 = *(const short8*)&Pl[wave][l15 * 72 + 32 + quad * 8];
#pragma unroll
            for (int nb = 0; nb < 4; ++nb) {
                const short8 vf0 = *(const short8*)&Vt[(nb * 16 + l15) * 64 + ph0];
                const short8 vf1 = *(const short8*)&Vt[(nb * 16 + l15) * 64 + ph1];
                o[nb] = MFMA16(pf0, vf0, o[nb]);
                o[nb] = MFMA16(pf1, vf1, o[nb]);
            }
        }

#pragma unroll
        for (int r = 0; r < 4; ++r) {
            float l = lsum[r];
            l += __shfl_xor(l, 1);
            l += __shfl_xor(l, 2);
            l += __shfl_xor(l, 4);
            l += __shfl_xor(l, 8);
            const float inv = 1.0f / l;
            const int row = q0w + 4 * quad + r;
#pragma unroll
            for (int nb = 0; nb < 4; ++nb)
                CTX[base + (size_t)row * D_ + nb * 16 + l15] = f_to_bf16(o[nb][r] * inv);
        }
    }
}

// ---------------------------------------------------------------------------
extern "C" void kernel_launch(void* const* d_in, const int* in_sizes, int n_in,
                              void* d_out, int out_size, void* d_ws, size_t ws_size,
                              hipStream_t stream) {
    (void)in_sizes; (void)n_in; (void)out_size; (void)ws_size;

    const unsigned int* xraw = (const unsigned int*)d_in[0];
    const void* Wq = d_in[1];
    const void* Wk = d_in[2];
    const void* Wv = d_in[3];
    const void* Wo = d_in[4];

    const size_t NE = (size_t)B_ * S_ * D_;   // 8388608
    const size_t NW = (size_t)D_ * D_;        // 1048576

    // ws layout: [xb: NE][wqkv: 3*NW][wob: NW][q: NE][k: NE][VT: NE]
    char* wsb = (char*)d_ws;
    short* xb   = (short*)wsb;                  wsb += NE * sizeof(short);
    short* wqkv = (short*)wsb;                  wsb += 3 * NW * sizeof(short);
    short* wob  = (short*)wsb;                  wsb += NW * sizeof(short);
    short* q    = (short*)wsb;                  wsb += NE * sizeof(short);
    short* k    = (short*)wsb;                  wsb += NE * sizeof(short);
    short* VT   = (short*)wsb;                  wsb += NE * sizeof(short);
    short* ctx  = xb;

    const int conv_blocks = (int)((NE + 4 * NW) / 8 / 256);  // 6144
    convert_all_kernel<<<conv_blocks, 256, 0, stream>>>(
        (const void*)xraw, Wq, Wk, Wv, Wo, xb, xraw);

    const dim3 qkv_grid(B_ * S_ / 256, 3 * D_ / 128, 1);  // 32 x 24 = 768 = 3 rounds
    gemm_qkv256_kernel<<<qkv_grid, 512, 0, stream>>>(xb, wqkv, q, k, VT);

    const dim3 attn_grid(H_, S_ / 128, B_);  // 16 x 16 x 4
    attn_kernel<<<attn_grid, 256, 0, stream>>>(q, k, VT, ctx);

    const dim3 gemm_grid(B_ * S_ / 256, D_ / 128, 1);  // 32 x 8 = 256 = 1 round
    gemm_xwT_kernel<<<gemm_grid, 512, 0, stream>>>(ctx, wob, d_out, xraw);
}